// Round 14
// baseline (49.536 us; speedup 1.0000x reference)
//
#include <hip/hip_runtime.h>
#include <hip/hip_bf16.h>
#include <hip/hip_fp16.h>

typedef unsigned int uint;
typedef unsigned short ushort;
typedef __attribute__((ext_vector_type(4))) float f32x4;
typedef __attribute__((ext_vector_type(8))) _Float16 f16x8;

// async global->LDS, 16B per lane; LDS dest is wave-uniform-base + lane*16 (linear)
#define LDS16(gp, lp)                                                                    \
  __builtin_amdgcn_global_load_lds((const __attribute__((address_space(1))) uint*)(gp),  \
                                   (__attribute__((address_space(3))) uint*)(lp), 16, 0, 0)

// pack two f32 -> one u32 of two f16 (RTZ)
__device__ __forceinline__ uint pk_f16(float a, float b) {
  __fp16 __attribute__((ext_vector_type(2))) r = __builtin_amdgcn_cvt_pkrtz(a, b);
  union { decltype(r) v; uint u; } c;
  c.v = r;
  return c.u;
}

// ---------------------------------------------------------------------------
// Kernel 1: W (1024x511 f32, row-major) -> transposed f16 [512][1024],
// col 511 zero-padded. LDS 64x65 tile transpose keeps both sides coalesced.
// ---------------------------------------------------------------------------
__global__ __launch_bounds__(256) void prep_w(const float* __restrict__ W,
                                              _Float16* __restrict__ WT) {
  __shared__ float t[64][65];
  const int tid = threadIdx.x;
  const int k0 = (blockIdx.x >> 3) * 64;
  const int n0 = (blockIdx.x & 7) * 64;
#pragma unroll
  for (int i = 0; i < 16; ++i) {
    int idx = i * 256 + tid;
    int kk = idx >> 6, nn = idx & 63;
    int n = n0 + nn;
    t[kk][nn] = (n < 511) ? W[(size_t)(k0 + kk) * 511 + n] : 0.f;
  }
  __syncthreads();
#pragma unroll
  for (int i = 0; i < 16; ++i) {
    int idx = i * 256 + tid;
    int nn = idx >> 6, kk = idx & 63;
    WT[(size_t)(n0 + nn) * 1024 + k0 + kk] = (_Float16)t[kk][nn];
  }
}

// ---------------------------------------------------------------------------
// Kernel 2 (FUSED): 64 rows x full 512 cols per block -> 64x10 out.
// ALL staging via global_load_lds (A as f32, converted at read time):
// the per-phase serial chain {vmcnt->cvt->ds_write->lgkmcnt->barrier} of
// r6-r13 is gone. Phase = vmcnt(5); barrier; compute; barrier; issue(t+2).
// 5 uniform DMA issues/thread/tile, 2 tiles in flight, never drain mid-loop.
// LDS: B 2x64KB (f16) + A 2x16KB (f32) = 160 KiB exactly.
// ---------------------------------------------------------------------------
__global__ __launch_bounds__(1024, 1) void gemm_tree(const float* __restrict__ X,
                                                     const _Float16* __restrict__ WT,
                                                     const float* __restrict__ bvec,
                                                     const float* __restrict__ LL,
                                                     float* __restrict__ out) {
  __shared__ _Float16 ldsB[2][512 * 64];  // 128 KB; reused by stage 2
  __shared__ float ldsA[2][64 * 64];      // 32 KB, f32 [row][16B-chunk swizzled]

  const int tid = threadIdx.x;            // 0..1023
  const int lane = tid & 63;
  const int w = tid >> 6;                 // 0..15
  const int wr = w >> 3, wc = w & 7;      // 2(M) x 8(N)
  const int l16 = lane & 15;
  const int g = lane >> 4;
  const int rbase = blockIdx.x * 64;

  // A DMA mapping: thread l -> LDS slot l (16B); slot (r, c') holds global
  // chunk c = c' ^ ((r&7)<<1)  (within-row XOR swizzle, bijective)
  const int a_r = tid >> 4;
  const int a_cp = tid & 15;
  const int a_c = a_cp ^ ((a_r & 7) << 1);
  const float* aSrcBase = X + (size_t)(rbase + a_r) * 1024 + a_c * 4;

  f32x4 acc[2][4];
#pragma unroll
  for (int i = 0; i < 2; ++i)
#pragma unroll
    for (int j = 0; j < 4; ++j) acc[i][j] = (f32x4)0.f;

  auto issue = [&](int buf, int kt) {
    // A: 1 gload_lds (f32, 16B)
    LDS16(aSrcBase + kt * 64, &ldsA[buf][tid * 4]);
    // B: 4 gload_lds (pre-swizzled source)
#pragma unroll
    for (int i = 0; i < 4; ++i) {
      int l = tid + 1024 * i;
      int c = l >> 3, gp = l & 7;
      int gs = gp ^ (c & 7);
      LDS16(WT + (size_t)c * 1024 + kt * 64 + gs * 8, &ldsB[buf][l * 8]);
    }
  };

  auto compute = [&](int buf) {
#pragma unroll
    for (int kk = 0; kk < 2; ++kk) {
      f16x8 b[4], a[2];
#pragma unroll
      for (int ni = 0; ni < 4; ++ni) {
        int c = wc * 64 + ni * 16 + l16;
        b[ni] = *(const f16x8*)&ldsB[buf][c * 64 + (((kk * 4 + g) ^ (c & 7)) * 8)];
      }
#pragma unroll
      for (int mi = 0; mi < 2; ++mi) {
        int r = wr * 32 + mi * 16 + l16;
        int c0 = kk * 8 + g * 2;                       // even 16B-chunk index
        int c0s = c0 ^ ((r & 7) << 1);                 // swizzled (odd partner +1)
        const f32x4 lo = *(const f32x4*)&ldsA[buf][r * 64 + c0s * 4];
        const f32x4 hi = *(const f32x4*)&ldsA[buf][r * 64 + (c0s + 1) * 4];
        union { uint u[4]; f16x8 v; } cv;
        cv.u[0] = pk_f16(lo[0], lo[1]);
        cv.u[1] = pk_f16(lo[2], lo[3]);
        cv.u[2] = pk_f16(hi[0], hi[1]);
        cv.u[3] = pk_f16(hi[2], hi[3]);
        a[mi] = cv.v;
      }
      __builtin_amdgcn_s_setprio(1);
#pragma unroll
      for (int mi = 0; mi < 2; ++mi)
#pragma unroll
        for (int ni = 0; ni < 4; ++ni)
          acc[mi][ni] = __builtin_amdgcn_mfma_f32_16x16x32_f16(a[mi], b[ni], acc[mi][ni], 0, 0, 0);
      __builtin_amdgcn_s_setprio(0);
    }
  };

  // prologue: tiles 0 and 1 in flight (5 loads/thread each)
  issue(0, 0);
  issue(1, 1);

#pragma unroll
  for (int t = 0; t < 16; ++t) {
    const int buf = t & 1;
    if (t < 15) {
      asm volatile("s_waitcnt vmcnt(5)" ::: "memory");  // tile t landed; t+1 flying
    } else {
      asm volatile("s_waitcnt vmcnt(0)" ::: "memory");  // last tile
    }
    __builtin_amdgcn_sched_barrier(0);
    __builtin_amdgcn_s_barrier();                       // everyone's tile-t data ready
    compute(buf);
    __builtin_amdgcn_s_barrier();                       // all waves done reading buf
    __builtin_amdgcn_sched_barrier(0);
    if (t + 2 < 16) issue(buf, t + 2);                  // refill this buf for t+2
  }

  // ---- stage 2a: sigmoid -> P in LDS (padded stride 520) ----
  __half* plds = (__half*)&ldsB[0][0];                    // 64 x 520 = 66.5 KB
  f32x4* red = (f32x4*)((char*)&ldsB[0][0] + 68 * 1024);  // [4 rg][3][64] = 12 KB
#pragma unroll
  for (int mi = 0; mi < 2; ++mi) {
#pragma unroll
    for (int ni = 0; ni < 4; ++ni) {
      int gc = wc * 64 + ni * 16 + l16;
      float bias = (gc < 511) ? bvec[gc] : 0.f;
#pragma unroll
      for (int q = 0; q < 4; ++q) {
        int lr = wr * 32 + mi * 16 + g * 4 + q;  // local row 0..63
        float z = acc[mi][ni][q] + bias;
        float pv = 1.f / (1.f + __expf(-z));
        plds[lr * 520 + gc] = __float2half(pv);
      }
    }
  }
  __syncthreads();

  // ---- stage 2b: tree propagation + leaf MFMA ----
  const int rg = w >> 2, tw = w & 3;
  const int r = lane & 15;
  const int col = r;

  f16x8 bfr[4];
#pragma unroll
  for (int tt = 0; tt < 4; ++tt) {
    int t = tw * 4 + tt;
#pragma unroll
    for (int p = 0; p < 8; ++p) {
      int k0 = t * 32 + g * 8 + p;
      bfr[tt][p] = (col < 10) ? (_Float16)LL[k0 * 10 + col] : (_Float16)0.f;
    }
  }

  const __half* prow = &plds[(rg * 16 + r) * 520];
  f32x4 tacc = (f32x4)0.f;
#pragma unroll
  for (int tt = 0; tt < 4; ++tt) {
    const int t = tw * 4 + tt;
    const int L0 = g * 8 + 32 * t;
    float pref = 1.f;
#pragma unroll
    for (int k = 0; k < 6; ++k) {
      int node = L0 >> (9 - k);
      int bit = (L0 >> (8 - k)) & 1;
      float pv = __half2float(prow[(1 << k) - 1 + node]);
      pref *= bit ? pv : (1.f - pv);
    }
    float p6 = __half2float(prow[63 + (L0 >> 3)]);
    float p7a = __half2float(prow[127 + (L0 >> 2)]);
    float p7b = __half2float(prow[128 + (L0 >> 2)]);
    float p80 = __half2float(prow[255 + (L0 >> 1)]);
    float p81 = __half2float(prow[256 + (L0 >> 1)]);
    float p82 = __half2float(prow[257 + (L0 >> 1)]);
    float p83 = __half2float(prow[258 + (L0 >> 1)]);
    float u1 = pref * p6, u0 = pref - u1;
    float v01 = u0 * p7a, v00 = u0 - v01;
    float v11 = u1 * p7b, v10 = u1 - v11;
    float pr1 = v00 * p80, pr0 = v00 - pr1;
    float pr3 = v01 * p81, pr2 = v01 - pr3;
    float pr5 = v10 * p82, pr4 = v10 - pr5;
    float pr7 = v11 * p83, pr6 = v11 - pr7;
    f16x8 af;
    af[0] = (_Float16)pr0; af[1] = (_Float16)pr1;
    af[2] = (_Float16)pr2; af[3] = (_Float16)pr3;
    af[4] = (_Float16)pr4; af[5] = (_Float16)pr5;
    af[6] = (_Float16)pr6; af[7] = (_Float16)pr7;
    tacc = __builtin_amdgcn_mfma_f32_16x16x32_f16(af, bfr[tt], tacc, 0, 0, 0);
  }

  if (tw > 0) red[(rg * 3 + (tw - 1)) * 64 + lane] = tacc;
  __syncthreads();

  if (tw == 0 && col < 10) {
    f32x4 a1 = red[(rg * 3 + 0) * 64 + lane];
    f32x4 a2 = red[(rg * 3 + 1) * 64 + lane];
    f32x4 a3 = red[(rg * 3 + 2) * 64 + lane];
#pragma unroll
    for (int q = 0; q < 4; ++q)
      out[(size_t)(rbase + rg * 16 + g * 4 + q) * 10 + col] =
          tacc[q] + a1[q] + a2[q] + a3[q];
  }
}

// ---------------------------------------------------------------------------
extern "C" void kernel_launch(void* const* d_in, const int* in_sizes, int n_in,
                              void* d_out, int out_size, void* d_ws, size_t ws_size,
                              hipStream_t stream) {
  const float* X = (const float*)d_in[0];
  const float* W = (const float*)d_in[1];
  const float* bv = (const float*)d_in[2];
  const float* LL = (const float*)d_in[3];
  float* out = (float*)d_out;

  _Float16* WT = (_Float16*)d_ws;  // 1 MB

  prep_w<<<128, 256, 0, stream>>>(W, WT);
  gemm_tree<<<256, 1024, 0, stream>>>(X, WT, bv, LL, out);
}